// Round 10
// baseline (231.840 us; speedup 1.0000x reference)
//
#include <hip/hip_runtime.h>
#include <hip/hip_bf16.h>

#define Bn 8
#define Sn 2048
#define Dn 512
#define Kn 64

typedef _Float16 half8 __attribute__((ext_vector_type(8)));
typedef _Float16 half4v __attribute__((ext_vector_type(4)));
typedef float f32x4 __attribute__((ext_vector_type(4)));

#define MFMA16(a,b,c) __builtin_amdgcn_mfma_f32_16x16x32_f16(a,b,c,0,0,0)
#define LOG2E 1.4426950408889634f

// LDS tiles [rows][64] f16 (128B rows), XOR-swizzled on 16B granules.
__device__ __forceinline__ half8 ldfrag(const _Float16* base, int row, int k8){
    const int scol = k8 ^ (row & 7);
    return *(const half8*)((const char*)base + row*128 + scol*16);
}

// Fragment layouts in global memory (16B granules, lane = l4*16+l15):
//  Qh2/Kh2: granule (t*2+ks)*64+lane = M[t*16+l15][ks*32+l4*8 .. +8]   (t = global 16-row tile)
//  Vt2:     granule (((b*32+sc)*2+ks)*32+dt)*64+lane = V[dt*16+l15][sc*64+(ks*4+l4)*8 .. +8]
// Q pre-scaled by log2(e). Stats: z[s] = sum_q 2^(l2-64); CS[s] = -(64+log2 z).
// attn: P[q,s] = 2^(l2[q,s] + CS[s]) via MFMA C-init.

// ---- Kernel 0: W transpose+cast ----
__global__ __launch_bounds__(256) void wtrans_kernel(
    const float* __restrict__ Wk, const float* __restrict__ Wq,
    _Float16* __restrict__ Wt16)
{
    const int n = blockIdx.x;
    const int t = threadIdx.x;
    const float* src = (n < 64) ? Wq : Wk;
    const int nn = n & 63;
    #pragma unroll
    for (int i = 0; i < 2; ++i){
        const int k = t + 256*i;
        Wt16[(size_t)n*Dn + k] = (_Float16)src[(size_t)k*Kn + nn];
    }
}

// ---- Kernel 1: fused Q/K projection + V transpose (32 rows per block) ----
__global__ __launch_bounds__(256, 2) void prep_kernel(
    const float* __restrict__ X, const _Float16* __restrict__ Wt16,
    const float* __restrict__ bk, const float* __restrict__ bq,
    _Float16* __restrict__ Qh2, _Float16* __restrict__ Kh2,
    _Float16* __restrict__ Vt2)
{
    __shared__ _Float16 Xt[2][32*64];
    const int bid = blockIdx.x;
    const int b = bid & 7, sb32 = bid >> 3;
    const int tid = threadIdx.x, lane = tid & 63, w = tid >> 6;
    const int l15 = lane & 15, l4 = lane >> 4;

    const int srow = tid >> 3, sg = tid & 7;
    const float* Xs = X + ((size_t)(b*Sn + sb32*32) + srow)*Dn + sg*8;
    const int sdst = srow*128 + (((sg ^ (srow & 7) ^ (srow >> 3)) & 7) * 16);

    const int n0 = w*32 + l15;
    const _Float16* Wp0 = Wt16 + (size_t)n0*Dn + l4*8;
    const _Float16* Wp1 = Wp0 + (size_t)16*Dn;

    f32x4 acc[2][2];
    #pragma unroll
    for (int i = 0; i < 2; ++i)
        #pragma unroll
        for (int j = 0; j < 2; ++j){ f32x4 z = {0.f,0.f,0.f,0.f}; acc[i][j] = z; }

    {
        const float4 v0 = *(const float4*)(Xs);
        const float4 v1 = *(const float4*)(Xs + 4);
        half8 h;
        h[0]=(_Float16)v0.x; h[1]=(_Float16)v0.y; h[2]=(_Float16)v0.z; h[3]=(_Float16)v0.w;
        h[4]=(_Float16)v1.x; h[5]=(_Float16)v1.y; h[6]=(_Float16)v1.z; h[7]=(_Float16)v1.w;
        *(half8*)((char*)Xt[0] + sdst) = h;
    }
    __syncthreads();

    const int dcol = w*16 + l15;
    #pragma unroll
    for (int kc = 0; kc < 8; ++kc){
        const _Float16* XtC = Xt[kc & 1];
        float4 nv0, nv1;
        if (kc < 7){
            nv0 = *(const float4*)(Xs + (kc+1)*64);
            nv1 = *(const float4*)(Xs + (kc+1)*64 + 4);
        }
        const half8 wf00 = *(const half8*)(Wp0 + kc*64);
        const half8 wf01 = *(const half8*)(Wp0 + kc*64 + 32);
        const half8 wf10 = *(const half8*)(Wp1 + kc*64);
        const half8 wf11 = *(const half8*)(Wp1 + kc*64 + 32);
        #pragma unroll
        for (int ks = 0; ks < 2; ++ks){
            #pragma unroll
            for (int qt = 0; qt < 2; ++qt){
                const int rw = qt*16 + l15;
                const int g = ((ks*4 + l4) ^ (rw & 7) ^ (rw >> 3)) & 7;
                const half8 a = *(const half8*)((const char*)XtC + rw*128 + g*16);
                acc[qt][0] = MFMA16(a, ks ? wf01 : wf00, acc[qt][0]);
                acc[qt][1] = MFMA16(a, ks ? wf11 : wf10, acc[qt][1]);
            }
        }
        {
            half8 hv;
            #pragma unroll
            for (int e = 0; e < 8; ++e){
                const int rw = l4*8 + e;
                const int g = ((dcol >> 3) ^ e ^ l4) & 7;
                hv[e] = XtC[rw*64 + g*8 + (dcol & 7)];
            }
            const size_t G = (((size_t)(b*32 + (sb32 >> 1))*2 + (sb32 & 1))*32 + kc*4 + w)*64 + lane;
            *(half8*)(Vt2 + G*8) = hv;
        }
        if (kc < 7){
            half8 h;
            h[0]=(_Float16)nv0.x; h[1]=(_Float16)nv0.y; h[2]=(_Float16)nv0.z; h[3]=(_Float16)nv0.w;
            h[4]=(_Float16)nv1.x; h[5]=(_Float16)nv1.y; h[6]=(_Float16)nv1.z; h[7]=(_Float16)nv1.w;
            *(half8*)((char*)Xt[(kc+1) & 1] + sdst) = h;
        }
        __syncthreads();
    }

    _Float16* tile16 = &Xt[0][0];
    #pragma unroll
    for (int qt = 0; qt < 2; ++qt){
        const int ql = qt*16 + l4*4;
        #pragma unroll
        for (int nt = 0; nt < 2; ++nt){
            const int n = w*32 + nt*16 + l15;
            const bool isQ = (n < 64);
            const float bias = isQ ? bq[n] : bk[n - 64];
            const float scale = isQ ? LOG2E : 1.0f;
            #pragma unroll
            for (int r = 0; r < 4; ++r)
                tile16[(ql + r)*128 + n] = (_Float16)((acc[qt][nt][r] + bias) * scale);
        }
    }
    __syncthreads();
    #pragma unroll
    for (int i = 0; i < 2; ++i){
        const int g = tid + 256*i;
        const int isK = g >> 8, qtl = (g >> 7) & 1, ks = (g >> 6) & 1, ln = g & 63;
        const int l4g = ln >> 4, l15g = ln & 15;
        const half8 h = *(const half8*)&tile16[(qtl*16 + l15g)*128 + isK*64 + ks*32 + l4g*8];
        const size_t tg = (size_t)b*128 + sb32*2 + qtl;
        _Float16* dst = (isK ? Kh2 : Qh2) + ((tg*2 + ks)*64 + ln)*8;
        *(half8*)dst = h;
    }
}

// ---- Kernel 2: per-(b,s) column denominators (base-2, fixed M0=64) ----
#define SBODY(QC0,QC1,QC2,QC3, QN0,QN1,QN2,QN3) do { \
    QN0 = *(const half8*)(Qp); \
    QN1 = *(const half8*)(Qp + 1024); \
    QN2 = *(const half8*)(Qp + 2048); \
    QN3 = *(const half8*)(Qp + 3072); \
    Qp += 8192; \
    f32x4 c0 = cinit, c1 = cinit; \
    c0 = MFMA16(ka0, QC0, c0); c0 = MFMA16(ka1, QC1, c0); \
    c1 = MFMA16(ka0, QC2, c1); c1 = MFMA16(ka1, QC3, c1); \
    _Pragma("unroll") \
    for (int r = 0; r < 4; ++r) \
        z[r] += exp2f(c0[r]) + exp2f(c1[r]); \
} while(0)

__global__ __launch_bounds__(512, 2) void stats_kernel(
    const _Float16* __restrict__ Qh2, const _Float16* __restrict__ Kh2,
    float* __restrict__ CS)
{
    __shared__ float zred[2][64];
    const int bid = blockIdx.x;
    const int b = bid & 7, stb = bid >> 3;
    const int tid = threadIdx.x, lane = tid & 63, w = tid >> 6;
    const int l15 = lane & 15, l4 = lane >> 4;
    const int sw = w & 3, qh = w >> 2, qh2 = qh*2;

    const half8 ka0 = *(const half8*)(Kh2 + ((size_t)((b*128 + stb*4 + sw)*2 + 0)*64 + lane)*8);
    const half8 ka1 = *(const half8*)(Kh2 + ((size_t)((b*128 + stb*4 + sw)*2 + 1)*64 + lane)*8);

    const char* Qp = (const char*)Qh2 + (size_t)(b*128 + qh2)*2048 + lane*16;

    const f32x4 cinit = {-64.f, -64.f, -64.f, -64.f};
    float z[4] = {0.f, 0.f, 0.f, 0.f};

    half8 qbA0, qbA1, qbA2, qbA3, qbB0, qbB1, qbB2, qbB3;
    qbA0 = *(const half8*)(Qp);
    qbA1 = *(const half8*)(Qp + 1024);
    qbA2 = *(const half8*)(Qp + 2048);
    qbA3 = *(const half8*)(Qp + 3072);
    Qp += 8192;

    for (int qc = 0; qc < 32; qc += 2){
        SBODY(qbA0,qbA1,qbA2,qbA3, qbB0,qbB1,qbB2,qbB3);
        SBODY(qbB0,qbB1,qbB2,qbB3, qbA0,qbA1,qbA2,qbA3);
    }
    #pragma unroll
    for (int d = 1; d < 16; d <<= 1)
        #pragma unroll
        for (int r = 0; r < 4; ++r)
            z[r] += __shfl_xor(z[r], d);
    if (l15 == 0){
        const int sl = sw*16 + l4*4;
        #pragma unroll
        for (int r = 0; r < 4; ++r) zred[qh][sl+r] = z[r];
    }
    __syncthreads();
    if (tid < 64)
        CS[b*Sn + stb*64 + tid] = -(64.0f + __log2f(zred[0][tid] + zred[1][tid]));
}

// ---- Kernel 3: attn, 128q x 128d blocks, 8 waves, 2 blocks/CU, reg K/V ----
#define WRP(CUR, QT, C) do { \
    half4v p; \
    p[0] = (_Float16)exp2f(C[0]); \
    p[1] = (_Float16)exp2f(C[1]); \
    p[2] = (_Float16)exp2f(C[2]); \
    p[3] = (_Float16)exp2f(C[3]); \
    *(half4v*)((char*)Pt[CUR] + pwo[QT]) = p; \
} while(0)

#define ABODY(CUR, KA, KAN, VB, VBN, CSA, CSN) do { \
    f32x4 c0 = {CSA.x, CSA.y, CSA.z, CSA.w}; \
    f32x4 c1 = c0, c2 = c0, c3 = c0; \
    c0 = MFMA16(KA[0], qb[0][0], c0); c0 = MFMA16(KA[1], qb[0][1], c0); \
    c1 = MFMA16(KA[0], qb[1][0], c1); c1 = MFMA16(KA[1], qb[1][1], c1); \
    c2 = MFMA16(KA[0], qb[2][0], c2); c2 = MFMA16(KA[1], qb[2][1], c2); \
    c3 = MFMA16(KA[0], qb[3][0], c3); c3 = MFMA16(KA[1], qb[3][1], c3); \
    KAN[0] = *(const half8*)(Kp); \
    KAN[1] = *(const half8*)(Kp + 1024); \
    Kp += 8192; \
    CSN = *(const float4*)Cp; Cp += 64; \
    WRP(CUR, 0, c0); WRP(CUR, 1, c1); WRP(CUR, 2, c2); WRP(CUR, 3, c3); \
    asm volatile("s_waitcnt lgkmcnt(0)\n\ts_barrier" ::: "memory"); \
    VBN[0] = *(const half8*)(Vp); \
    VBN[1] = *(const half8*)(Vp + 1024); \
    VBN[2] = *(const half8*)(Vp + 32768); \
    VBN[3] = *(const half8*)(Vp + 32768 + 1024); \
    Vp += 65536; \
    __builtin_amdgcn_s_setprio(1); \
    { const char* PB = (const char*)Pt[CUR]; \
      _Pragma("unroll") \
      for (int ks = 0; ks < 2; ++ks){ \
        const half8 pa0 = *(const half8*)(PB + pao[0][ks]); \
        const half8 pa1 = *(const half8*)(PB + pao[1][ks]); \
        const half8 pa2 = *(const half8*)(PB + pao[2][ks]); \
        const half8 pa3 = *(const half8*)(PB + pao[3][ks]); \
        _Pragma("unroll") \
        for (int dt = 0; dt < 2; ++dt){ \
            const half8 vb = VB[ks*2+dt]; \
            acc[0][dt] = MFMA16(pa0, vb, acc[0][dt]); \
            acc[1][dt] = MFMA16(pa1, vb, acc[1][dt]); \
            acc[2][dt] = MFMA16(pa2, vb, acc[2][dt]); \
            acc[3][dt] = MFMA16(pa3, vb, acc[3][dt]); \
        } \
      } } \
    __builtin_amdgcn_s_setprio(0); \
} while(0)

__global__ __launch_bounds__(512, 4) void attn_kernel(
    const _Float16* __restrict__ Qh2, const _Float16* __restrict__ Kh2,
    const _Float16* __restrict__ Vt2, const float* __restrict__ CS,
    float* __restrict__ out)
{
    __shared__ _Float16 Pt[2][128*64];   // 32 KB total -> 2 blocks/CU
    const int bid = blockIdx.x;
    const int b  = bid & 7;              // b-major -> one batch per XCD
    const int qi = (bid >> 3) & 15;
    const int dh = bid >> 7;             // 0..3 d-quarter (128 each)
    const int q0 = qi * 128;
    const int tid = threadIdx.x, lane = tid & 63, w = tid >> 6;  // w 0..7
    const int l15 = lane & 15, l4 = lane >> 4;
    const int st = w & 3, qh = w >> 2, dw = w & 3;

    // Q fragments: wave's 64q-half (4 qt x 2 ks)
    const size_t qgb = (size_t)b*128 + qi*8 + qh*4;
    half8 qb[4][2];
    #pragma unroll
    for (int qt = 0; qt < 4; ++qt)
        #pragma unroll
        for (int ks = 0; ks < 2; ++ks)
            qb[qt][ks] = *(const half8*)(Qh2 + (((qgb + qt)*2 + ks)*64 + lane)*8);

    // precomputed LDS offsets (P tile rows = 128 q, cols = 64 s)
    int pwo[4], pao[4][2];
    {
        const int sb2 = (st*16 + l4*4) * 2;
        #pragma unroll
        for (int qt = 0; qt < 4; ++qt){
            const int q_ = qh*64 + qt*16 + l15;
            pwo[qt] = q_*128 + (sb2 ^ ((q_ & 7) << 4));
            #pragma unroll
            for (int ks = 0; ks < 2; ++ks)
                pao[qt][ks] = q_*128 + (((ks*4 + l4) ^ (q_ & 7)) * 16);
        }
    }

    // streams (bumped pointers)
    const char* Kp = (const char*)Kh2 + (size_t)(b*128 + st)*2048 + lane*16;
    const float* Cp = CS + b*Sn + st*16 + l4*4;
    const char* Vp = (const char*)Vt2 + (size_t)(b*2048 + dh*8 + dw*2)*1024 + lane*16;

    // prologue: K(0), CS(0), V(0)
    half8 kaA[2], kaB[2], vbA[4], vbB[4];
    float4 csA, csB;
    kaA[0] = *(const half8*)(Kp);
    kaA[1] = *(const half8*)(Kp + 1024);
    Kp += 8192;
    csA = *(const float4*)Cp; Cp += 64;
    vbA[0] = *(const half8*)(Vp);
    vbA[1] = *(const half8*)(Vp + 1024);
    vbA[2] = *(const half8*)(Vp + 32768);
    vbA[3] = *(const half8*)(Vp + 32768 + 1024);
    Vp += 65536;

    f32x4 acc[4][2];
    #pragma unroll
    for (int i = 0; i < 4; ++i)
        #pragma unroll
        for (int j = 0; j < 2; ++j){ f32x4 zz4 = {0.f,0.f,0.f,0.f}; acc[i][j] = zz4; }

    for (int sc = 0; sc < 32; sc += 2){
        ABODY(0, kaA, kaB, vbA, vbB, csA, csB);
        ABODY(1, kaB, kaA, vbB, vbA, csB, csA);
    }

    float* ob = out + (size_t)(b*Sn + q0 + qh*64)*Dn + dh*128 + dw*32;
    #pragma unroll
    for (int qt = 0; qt < 4; ++qt){
        const int q = qt*16 + l4*4;
        #pragma unroll
        for (int dt = 0; dt < 2; ++dt){
            #pragma unroll
            for (int r = 0; r < 4; ++r)
                ob[(size_t)(q + r)*Dn + dt*16 + l15] = acc[qt][dt][r];
        }
    }
}

extern "C" void kernel_launch(void* const* d_in, const int* in_sizes, int n_in,
                              void* d_out, int out_size, void* d_ws, size_t ws_size,
                              hipStream_t stream)
{
    const float* X  = (const float*)d_in[0];
    const float* Wk = (const float*)d_in[1];
    const float* bk = (const float*)d_in[2];
    const float* Wq = (const float*)d_in[3];
    const float* bq = (const float*)d_in[4];
    float* out = (float*)d_out;

    char* ws = (char*)d_ws;
    _Float16* Qh2  = (_Float16*)ws;                                  // 2 MB
    _Float16* Kh2  = (_Float16*)(ws + ((size_t)2 << 20));            // 2 MB
    _Float16* Vt2  = (_Float16*)(ws + ((size_t)4 << 20));            // 16 MB
    float*    CS   = (float*)(ws + ((size_t)20 << 20));              // 64 KB (+guard)
    _Float16* Wt16 = (_Float16*)(ws + ((size_t)20 << 20) + (2 << 16)); // 128 KB

    wtrans_kernel<<<dim3(128), dim3(256), 0, stream>>>(Wk, Wq, Wt16);
    prep_kernel<<<dim3(Bn*(Sn/32)), dim3(256), 0, stream>>>(X, Wt16, bk, bq, Qh2, Kh2, Vt2);
    stats_kernel<<<dim3(Bn*(Sn/64)), dim3(512), 0, stream>>>(Qh2, Kh2, CS);
    attn_kernel<<<dim3(Bn*(Sn/128)*4), dim3(512), 0, stream>>>(Qh2, Kh2, Vt2, CS, out);
}

// Round 11
// 106.233 us; speedup vs baseline: 2.1824x; 2.1824x over previous
//
#include <hip/hip_runtime.h>
#include <hip/hip_bf16.h>

#define Bn 8
#define Sn 2048
#define Dn 512
#define Kn 64

typedef _Float16 half8 __attribute__((ext_vector_type(8)));
typedef _Float16 half4v __attribute__((ext_vector_type(4)));
typedef float f32x4 __attribute__((ext_vector_type(4)));

#define MFMA16(a,b,c) __builtin_amdgcn_mfma_f32_16x16x32_f16(a,b,c,0,0,0)
#define LOG2E 1.4426950408889634f

// Fragment layouts in global memory (16B granules, lane = l4*16+l15):
//  Qh2/Kh2: granule (t*2+ks)*64+lane = M[t*16+l15][ks*32+l4*8 .. +8]   (t = global 16-row tile)
//  Vt2:     granule (((b*32+sc)*2+ks)*32+dt)*64+lane = V[dt*16+l15][sc*64+(ks*4+l4)*8 .. +8]
//  Pg:      granule (((b*32+sc)*128+qt)*2+ks)*64+lane = P_hat[qt*16+l15][sc*64 + ks*32+l4*8 ..+8]
// Q pre-scaled by log2(e) -> logits are base-2.
// stats2: M[s] = max_q l2;  Z[s] = sum_q 2^(l2-64);  P_hat = 2^(l2 - M[s]) in f16;
//         CSV[s] = 2^(M[s] - 64 - log2 Z[s])  (f32 scale folded into V by vscale).
// attn3:  O = P_hat @ V'  (pure streaming GEMM, no LDS/barriers).

// ---- Kernel 0: W transpose+cast ----
__global__ __launch_bounds__(256) void wtrans_kernel(
    const float* __restrict__ Wk, const float* __restrict__ Wq,
    _Float16* __restrict__ Wt16)
{
    const int n = blockIdx.x;
    const int t = threadIdx.x;
    const float* src = (n < 64) ? Wq : Wk;
    const int nn = n & 63;
    #pragma unroll
    for (int i = 0; i < 2; ++i){
        const int k = t + 256*i;
        Wt16[(size_t)n*Dn + k] = (_Float16)src[(size_t)k*Kn + nn];
    }
}

// ---- Kernel 1: fused Q/K projection + V transpose (32 rows per block) ----
__global__ __launch_bounds__(256, 2) void prep_kernel(
    const float* __restrict__ X, const _Float16* __restrict__ Wt16,
    const float* __restrict__ bk, const float* __restrict__ bq,
    _Float16* __restrict__ Qh2, _Float16* __restrict__ Kh2,
    _Float16* __restrict__ Vt2)
{
    __shared__ _Float16 Xt[2][32*64];
    const int bid = blockIdx.x;
    const int b = bid & 7, sb32 = bid >> 3;
    const int tid = threadIdx.x, lane = tid & 63, w = tid >> 6;
    const int l15 = lane & 15, l4 = lane >> 4;

    const int srow = tid >> 3, sg = tid & 7;
    const float* Xs = X + ((size_t)(b*Sn + sb32*32) + srow)*Dn + sg*8;
    const int sdst = srow*128 + (((sg ^ (srow & 7) ^ (srow >> 3)) & 7) * 16);

    const int n0 = w*32 + l15;
    const _Float16* Wp0 = Wt16 + (size_t)n0*Dn + l4*8;
    const _Float16* Wp1 = Wp0 + (size_t)16*Dn;

    f32x4 acc[2][2];
    #pragma unroll
    for (int i = 0; i < 2; ++i)
        #pragma unroll
        for (int j = 0; j < 2; ++j){ f32x4 z = {0.f,0.f,0.f,0.f}; acc[i][j] = z; }

    {
        const float4 v0 = *(const float4*)(Xs);
        const float4 v1 = *(const float4*)(Xs + 4);
        half8 h;
        h[0]=(_Float16)v0.x; h[1]=(_Float16)v0.y; h[2]=(_Float16)v0.z; h[3]=(_Float16)v0.w;
        h[4]=(_Float16)v1.x; h[5]=(_Float16)v1.y; h[6]=(_Float16)v1.z; h[7]=(_Float16)v1.w;
        *(half8*)((char*)Xt[0] + sdst) = h;
    }
    __syncthreads();

    const int dcol = w*16 + l15;
    #pragma unroll
    for (int kc = 0; kc < 8; ++kc){
        const _Float16* XtC = Xt[kc & 1];
        float4 nv0, nv1;
        if (kc < 7){
            nv0 = *(const float4*)(Xs + (kc+1)*64);
            nv1 = *(const float4*)(Xs + (kc+1)*64 + 4);
        }
        const half8 wf00 = *(const half8*)(Wp0 + kc*64);
        const half8 wf01 = *(const half8*)(Wp0 + kc*64 + 32);
        const half8 wf10 = *(const half8*)(Wp1 + kc*64);
        const half8 wf11 = *(const half8*)(Wp1 + kc*64 + 32);
        #pragma unroll
        for (int ks = 0; ks < 2; ++ks){
            #pragma unroll
            for (int qt = 0; qt < 2; ++qt){
                const int rw = qt*16 + l15;
                const int g = ((ks*4 + l4) ^ (rw & 7) ^ (rw >> 3)) & 7;
                const half8 a = *(const half8*)((const char*)XtC + rw*128 + g*16);
                acc[qt][0] = MFMA16(a, ks ? wf01 : wf00, acc[qt][0]);
                acc[qt][1] = MFMA16(a, ks ? wf11 : wf10, acc[qt][1]);
            }
        }
        {
            half8 hv;
            #pragma unroll
            for (int e = 0; e < 8; ++e){
                const int rw = l4*8 + e;
                const int g = ((dcol >> 3) ^ e ^ l4) & 7;
                hv[e] = XtC[rw*64 + g*8 + (dcol & 7)];
            }
            const size_t G = (((size_t)(b*32 + (sb32 >> 1))*2 + (sb32 & 1))*32 + kc*4 + w)*64 + lane;
            *(half8*)(Vt2 + G*8) = hv;
        }
        if (kc < 7){
            half8 h;
            h[0]=(_Float16)nv0.x; h[1]=(_Float16)nv0.y; h[2]=(_Float16)nv0.z; h[3]=(_Float16)nv0.w;
            h[4]=(_Float16)nv1.x; h[5]=(_Float16)nv1.y; h[6]=(_Float16)nv1.z; h[7]=(_Float16)nv1.w;
            *(half8*)((char*)Xt[(kc+1) & 1] + sdst) = h;
        }
        __syncthreads();
    }

    _Float16* tile16 = &Xt[0][0];
    #pragma unroll
    for (int qt = 0; qt < 2; ++qt){
        const int ql = qt*16 + l4*4;
        #pragma unroll
        for (int nt = 0; nt < 2; ++nt){
            const int n = w*32 + nt*16 + l15;
            const bool isQ = (n < 64);
            const float bias = isQ ? bq[n] : bk[n - 64];
            const float scale = isQ ? LOG2E : 1.0f;
            #pragma unroll
            for (int r = 0; r < 4; ++r)
                tile16[(ql + r)*128 + n] = (_Float16)((acc[qt][nt][r] + bias) * scale);
        }
    }
    __syncthreads();
    #pragma unroll
    for (int i = 0; i < 2; ++i){
        const int g = tid + 256*i;
        const int isK = g >> 8, qtl = (g >> 7) & 1, ks = (g >> 6) & 1, ln = g & 63;
        const int l4g = ln >> 4, l15g = ln & 15;
        const half8 h = *(const half8*)&tile16[(qtl*16 + l15g)*128 + isK*64 + ks*32 + l4g*8];
        const size_t tg = (size_t)b*128 + sb32*2 + qtl;
        _Float16* dst = (isK ? Kh2 : Qh2) + ((tg*2 + ks)*64 + ln)*8;
        *(half8*)dst = h;
    }
}

// ---- Kernel 2: stats2 — two-pass: (M,Z) then P_hat write + CSV ----
__global__ __launch_bounds__(512) void stats2_kernel(
    const _Float16* __restrict__ Qh2, const _Float16* __restrict__ Kh2,
    _Float16* __restrict__ Pg, float* __restrict__ CSV)
{
    __shared__ float mred[8][64];
    __shared__ float zred[8][64];
    __shared__ float mfin[64];
    __shared__ char  tr[8][2048];
    const int bid = blockIdx.x;
    const int b = bid & 7, stb = bid >> 3;
    const int tid = threadIdx.x, lane = tid & 63, w = tid >> 6;
    const int l15 = lane & 15, l4 = lane >> 4;

    // K fragments for this 64-s tile (once)
    half8 ka[4][2];
    #pragma unroll
    for (int ssub = 0; ssub < 4; ++ssub)
        #pragma unroll
        for (int ks = 0; ks < 2; ++ks)
            ka[ssub][ks] = *(const half8*)((const char*)Kh2 +
                (((size_t)(b*128 + stb*4 + ssub)*2 + ks) << 10) + lane*16);

    const char* Qb = (const char*)Qh2 + ((size_t)(b*128 + w*16)*2 << 10) + lane*16;

    // ---- pass 1: per-s max and Z (offset 64) ----
    f32x4 m4[4], z4[4];
    #pragma unroll
    for (int s = 0; s < 4; ++s){
        f32x4 mi = {-3.0e38f,-3.0e38f,-3.0e38f,-3.0e38f};
        f32x4 zi = {0.f,0.f,0.f,0.f};
        m4[s] = mi; z4[s] = zi;
    }
    for (int qi = 0; qi < 16; ++qi){
        const half8 qb0 = *(const half8*)(Qb + qi*2048);
        const half8 qb1 = *(const half8*)(Qb + qi*2048 + 1024);
        #pragma unroll
        for (int ssub = 0; ssub < 4; ++ssub){
            f32x4 c = {0.f,0.f,0.f,0.f};
            c = MFMA16(ka[ssub][0], qb0, c);
            c = MFMA16(ka[ssub][1], qb1, c);
            #pragma unroll
            for (int r = 0; r < 4; ++r){
                m4[ssub][r] = fmaxf(m4[ssub][r], c[r]);
                z4[ssub][r] += exp2f(c[r] - 64.0f);
            }
        }
    }
    #pragma unroll
    for (int d = 1; d < 16; d <<= 1)
        #pragma unroll
        for (int ssub = 0; ssub < 4; ++ssub)
            #pragma unroll
            for (int r = 0; r < 4; ++r){
                m4[ssub][r] = fmaxf(m4[ssub][r], __shfl_xor(m4[ssub][r], d));
                z4[ssub][r] += __shfl_xor(z4[ssub][r], d);
            }
    if (l15 == 0){
        #pragma unroll
        for (int ssub = 0; ssub < 4; ++ssub)
            #pragma unroll
            for (int r = 0; r < 4; ++r){
                mred[w][ssub*16 + l4*4 + r] = m4[ssub][r];
                zred[w][ssub*16 + l4*4 + r] = z4[ssub][r];
            }
    }
    __syncthreads();
    if (tid < 64){
        float M = mred[0][tid], Z = zred[0][tid];
        #pragma unroll
        for (int ww = 1; ww < 8; ++ww){
            M = fmaxf(M, mred[ww][tid]);
            Z += zred[ww][tid];
        }
        mfin[tid] = M;
        CSV[b*Sn + stb*64 + tid] = exp2f(M - 64.0f - __log2f(Z));
    }
    __syncthreads();

    // ---- pass 2: P_hat = 2^(l2 - M[s]) -> f16 granules via LDS transpose ----
    float4 Mloc[4];
    #pragma unroll
    for (int ssub = 0; ssub < 4; ++ssub)
        Mloc[ssub] = *(const float4*)&mfin[ssub*16 + l4*4];

    char* trw = tr[w];
    char* PgB = (char*)Pg + (size_t)(b*32 + stb)*262144 + (size_t)(w*16)*2048 + lane*16;
    for (int qi = 0; qi < 16; ++qi){
        const half8 qb0 = *(const half8*)(Qb + qi*2048);
        const half8 qb1 = *(const half8*)(Qb + qi*2048 + 1024);
        #pragma unroll
        for (int ssub = 0; ssub < 4; ++ssub){
            f32x4 c = {0.f,0.f,0.f,0.f};
            c = MFMA16(ka[ssub][0], qb0, c);
            c = MFMA16(ka[ssub][1], qb1, c);
            half4v pq;
            pq[0] = (_Float16)exp2f(c[0] - Mloc[ssub].x);
            pq[1] = (_Float16)exp2f(c[1] - Mloc[ssub].y);
            pq[2] = (_Float16)exp2f(c[2] - Mloc[ssub].z);
            pq[3] = (_Float16)exp2f(c[3] - Mloc[ssub].w);
            *(half4v*)(trw + l15*128 + (((ssub*2 + (l4>>1)) ^ (l15 & 7)) << 4) + ((l4 & 1) << 3)) = pq;
        }
        #pragma unroll
        for (int ks = 0; ks < 2; ++ks){
            const half8 g = *(const half8*)(trw + l15*128 + (((ks*4 + l4) ^ (l15 & 7)) << 4));
            *(half8*)(PgB + qi*2048 + ks*1024) = g;
        }
    }
}

// ---- Kernel 3: vscale — V *= CSV[s] in place (f16) ----
__global__ __launch_bounds__(256) void vscale_kernel(
    _Float16* __restrict__ Vt2, const float* __restrict__ CSV)
{
    const int o0 = blockIdx.x*256 + threadIdx.x;
    #pragma unroll
    for (int rep = 0; rep < 2; ++rep){
        const int oo = o0 + rep*524288;
        const int ln = oo & 63;
        const int G  = oo >> 6;
        const int ks = (G >> 5) & 1;
        const int sc = (G >> 6) & 31;
        const int b  = G >> 11;
        const int s0 = sc*64 + ks*32 + (ln >> 4)*8;
        const float4 c0 = *(const float4*)&CSV[b*Sn + s0];
        const float4 c1 = *(const float4*)&CSV[b*Sn + s0 + 4];
        half8 v = ((half8*)Vt2)[oo];
        v[0] = (_Float16)((float)v[0] * c0.x);
        v[1] = (_Float16)((float)v[1] * c0.y);
        v[2] = (_Float16)((float)v[2] * c0.z);
        v[3] = (_Float16)((float)v[3] * c0.w);
        v[4] = (_Float16)((float)v[4] * c1.x);
        v[5] = (_Float16)((float)v[5] * c1.y);
        v[6] = (_Float16)((float)v[6] * c1.z);
        v[7] = (_Float16)((float)v[7] * c1.w);
        ((half8*)Vt2)[oo] = v;
    }
}

// ---- Kernel 4: attn3 — O = P_hat @ V' : pure streaming GEMM ----
#define GB(PA, PAN, VB, VBN) do { \
    _Pragma("unroll") \
    for (int qt = 0; qt < 4; ++qt){ \
        PAN[qt][0] = *(const half8*)(PaP + qt*2048); \
        PAN[qt][1] = *(const half8*)(PaP + qt*2048 + 1024); \
    } \
    PaP += 262144; \
    _Pragma("unroll") \
    for (int dt = 0; dt < 4; ++dt){ \
        VBN[0][dt] = *(const half8*)(VbP + dt*1024); \
        VBN[1][dt] = *(const half8*)(VbP + 32768 + dt*1024); \
    } \
    VbP += 65536; \
    _Pragma("unroll") \
    for (int qt = 0; qt < 4; ++qt) \
        _Pragma("unroll") \
        for (int dt = 0; dt < 4; ++dt){ \
            acc[qt][dt] = MFMA16(PA[qt][0], VB[0][dt], acc[qt][dt]); \
            acc[qt][dt] = MFMA16(PA[qt][1], VB[1][dt], acc[qt][dt]); \
        } \
} while(0)

__global__ __launch_bounds__(256) void attn3_kernel(
    const _Float16* __restrict__ Pg, const _Float16* __restrict__ Vt2,
    float* __restrict__ out)
{
    const int bid = blockIdx.x;
    const int b  = bid & 7;             // b-major -> one batch per XCD
    const int qi = (bid >> 3) & 31;     // 64-q tile
    const int dh = bid >> 8;            // 0..1 d-half
    const int tid = threadIdx.x, lane = tid & 63, w = tid >> 6;  // w 0..3
    const int l15 = lane & 15, l4 = lane >> 4;

    const char* PaP = (const char*)Pg + (size_t)(b*32)*262144 + (size_t)(qi*4)*2048 + lane*16;
    const char* VbP = (const char*)Vt2 + ((size_t)(b*2048 + dh*16 + w*4) << 10) + lane*16;

    half8 paA[4][2], paB[4][2], vbA[2][4], vbB[2][4];
    // prologue: load sc=0 into A-buffers
    #pragma unroll
    for (int qt = 0; qt < 4; ++qt){
        paA[qt][0] = *(const half8*)(PaP + qt*2048);
        paA[qt][1] = *(const half8*)(PaP + qt*2048 + 1024);
    }
    PaP += 262144;
    #pragma unroll
    for (int dt = 0; dt < 4; ++dt){
        vbA[0][dt] = *(const half8*)(VbP + dt*1024);
        vbA[1][dt] = *(const half8*)(VbP + 32768 + dt*1024);
    }
    VbP += 65536;

    f32x4 acc[4][4];
    #pragma unroll
    for (int i = 0; i < 4; ++i)
        #pragma unroll
        for (int j = 0; j < 4; ++j){ f32x4 z = {0.f,0.f,0.f,0.f}; acc[i][j] = z; }

    for (int sc = 0; sc < 16; ++sc){
        GB(paA, paB, vbA, vbB);
        GB(paB, paA, vbB, vbA);
    }
    // note: last GB prefetches one tile past sc=31 — lands in pad region of ws.

    float* ob = out + (size_t)(b*Sn + qi*64)*Dn + dh*256 + w*64;
    #pragma unroll
    for (int qt = 0; qt < 4; ++qt){
        const int q = qt*16 + l4*4;
        #pragma unroll
        for (int dt = 0; dt < 4; ++dt){
            #pragma unroll
            for (int r = 0; r < 4; ++r)
                ob[(size_t)(q + r)*Dn + dt*16 + l15] = acc[qt][dt][r];
        }
    }
}

extern "C" void kernel_launch(void* const* d_in, const int* in_sizes, int n_in,
                              void* d_out, int out_size, void* d_ws, size_t ws_size,
                              hipStream_t stream)
{
    const float* X  = (const float*)d_in[0];
    const float* Wk = (const float*)d_in[1];
    const float* bk = (const float*)d_in[2];
    const float* Wq = (const float*)d_in[3];
    const float* bq = (const float*)d_in[4];
    float* out = (float*)d_out;

    char* ws = (char*)d_ws;
    _Float16* Qh2  = (_Float16*)ws;                                    // 2 MB
    _Float16* Kh2  = (_Float16*)(ws + ((size_t)2 << 20));              // 2 MB
    _Float16* Vt2  = (_Float16*)(ws + ((size_t)4 << 20));              // 16 MB
    _Float16* Wt16 = (_Float16*)(ws + ((size_t)20 << 20));             // 128 KB
    float*    CSV  = (float*)(ws + ((size_t)20 << 20) + (1 << 18));    // 64 KB
    _Float16* Pg   = (_Float16*)(ws + ((size_t)21 << 20));             // 64 MB + pad

    wtrans_kernel<<<dim3(128), dim3(256), 0, stream>>>(Wk, Wq, Wt16);
    prep_kernel<<<dim3(Bn*(Sn/32)), dim3(256), 0, stream>>>(X, Wt16, bk, bq, Qh2, Kh2, Vt2);
    stats2_kernel<<<dim3(Bn*(Sn/64)), dim3(512), 0, stream>>>(Qh2, Kh2, Pg, CSV);
    vscale_kernel<<<dim3(2048), dim3(256), 0, stream>>>(Vt2, CSV);
    attn3_kernel<<<dim3(Bn*(Sn/64)*2), dim3(256), 0, stream>>>(Pg, Vt2, out);
}

// Round 12
// 98.980 us; speedup vs baseline: 2.3423x; 1.0733x over previous
//
#include <hip/hip_runtime.h>
#include <hip/hip_bf16.h>

#define Bn 8
#define Sn 2048
#define Dn 512
#define Kn 64

typedef _Float16 half8 __attribute__((ext_vector_type(8)));
typedef _Float16 half4v __attribute__((ext_vector_type(4)));
typedef float f32x4 __attribute__((ext_vector_type(4)));

#define MFMA16(a,b,c) __builtin_amdgcn_mfma_f32_16x16x32_f16(a,b,c,0,0,0)
#define LOG2E 1.4426950408889634f

// LDS tiles [rows][64] f16 (128B rows), XOR-swizzled on 16B granules.
__device__ __forceinline__ half8 ldfrag(const _Float16* base, int row, int k8){
    const int scol = k8 ^ (row & 7);
    return *(const half8*)((const char*)base + row*128 + scol*16);
}

// Fragment layouts in global memory (16B granules, lane = l4*16+l15):
//  Qh2/Kh2: granule (t*2+ks)*64+lane = M[t*16+l15][ks*32+l4*8 .. +8]   (t = global 16-row tile)
//  Vt2:     granule (((b*32+sc)*2+ks)*32+dt)*64+lane = V[dt*16+l15][sc*64+(ks*4+l4)*8 .. +8]
// Q pre-scaled by log2(e). Stats: z[s] = sum_q 2^(l2-64); CS[s] = -(64+log2 z).
// attn: P[q,s] = 2^(l2[q,s] + CS[s]) via MFMA C-init.

// ---- Kernel 0: W transpose+cast ----
__global__ __launch_bounds__(256) void wtrans_kernel(
    const float* __restrict__ Wk, const float* __restrict__ Wq,
    _Float16* __restrict__ Wt16)
{
    const int n = blockIdx.x;
    const int t = threadIdx.x;
    const float* src = (n < 64) ? Wq : Wk;
    const int nn = n & 63;
    #pragma unroll
    for (int i = 0; i < 2; ++i){
        const int k = t + 256*i;
        Wt16[(size_t)n*Dn + k] = (_Float16)src[(size_t)k*Kn + nn];
    }
}

// ---- Kernel 1: fused Q/K projection + V transpose (32 rows per block) ----
__global__ __launch_bounds__(256, 2) void prep_kernel(
    const float* __restrict__ X, const _Float16* __restrict__ Wt16,
    const float* __restrict__ bk, const float* __restrict__ bq,
    _Float16* __restrict__ Qh2, _Float16* __restrict__ Kh2,
    _Float16* __restrict__ Vt2)
{
    __shared__ _Float16 Xt[2][32*64];
    const int bid = blockIdx.x;
    const int b = bid & 7, sb32 = bid >> 3;
    const int tid = threadIdx.x, lane = tid & 63, w = tid >> 6;
    const int l15 = lane & 15, l4 = lane >> 4;

    const int srow = tid >> 3, sg = tid & 7;
    const float* Xs = X + ((size_t)(b*Sn + sb32*32) + srow)*Dn + sg*8;
    const int sdst = srow*128 + (((sg ^ (srow & 7) ^ (srow >> 3)) & 7) * 16);

    const int n0 = w*32 + l15;
    const _Float16* Wp0 = Wt16 + (size_t)n0*Dn + l4*8;
    const _Float16* Wp1 = Wp0 + (size_t)16*Dn;

    f32x4 acc[2][2];
    #pragma unroll
    for (int i = 0; i < 2; ++i)
        #pragma unroll
        for (int j = 0; j < 2; ++j){ f32x4 z = {0.f,0.f,0.f,0.f}; acc[i][j] = z; }

    {
        const float4 v0 = *(const float4*)(Xs);
        const float4 v1 = *(const float4*)(Xs + 4);
        half8 h;
        h[0]=(_Float16)v0.x; h[1]=(_Float16)v0.y; h[2]=(_Float16)v0.z; h[3]=(_Float16)v0.w;
        h[4]=(_Float16)v1.x; h[5]=(_Float16)v1.y; h[6]=(_Float16)v1.z; h[7]=(_Float16)v1.w;
        *(half8*)((char*)Xt[0] + sdst) = h;
    }
    __syncthreads();

    const int dcol = w*16 + l15;
    #pragma unroll
    for (int kc = 0; kc < 8; ++kc){
        const _Float16* XtC = Xt[kc & 1];
        float4 nv0, nv1;
        if (kc < 7){
            nv0 = *(const float4*)(Xs + (kc+1)*64);
            nv1 = *(const float4*)(Xs + (kc+1)*64 + 4);
        }
        const half8 wf00 = *(const half8*)(Wp0 + kc*64);
        const half8 wf01 = *(const half8*)(Wp0 + kc*64 + 32);
        const half8 wf10 = *(const half8*)(Wp1 + kc*64);
        const half8 wf11 = *(const half8*)(Wp1 + kc*64 + 32);
        #pragma unroll
        for (int ks = 0; ks < 2; ++ks){
            #pragma unroll
            for (int qt = 0; qt < 2; ++qt){
                const int rw = qt*16 + l15;
                const int g = ((ks*4 + l4) ^ (rw & 7) ^ (rw >> 3)) & 7;
                const half8 a = *(const half8*)((const char*)XtC + rw*128 + g*16);
                acc[qt][0] = MFMA16(a, ks ? wf01 : wf00, acc[qt][0]);
                acc[qt][1] = MFMA16(a, ks ? wf11 : wf10, acc[qt][1]);
            }
        }
        {
            half8 hv;
            #pragma unroll
            for (int e = 0; e < 8; ++e){
                const int rw = l4*8 + e;
                const int g = ((dcol >> 3) ^ e ^ l4) & 7;
                hv[e] = XtC[rw*64 + g*8 + (dcol & 7)];
            }
            const size_t G = (((size_t)(b*32 + (sb32 >> 1))*2 + (sb32 & 1))*32 + kc*4 + w)*64 + lane;
            *(half8*)(Vt2 + G*8) = hv;
        }
        if (kc < 7){
            half8 h;
            h[0]=(_Float16)nv0.x; h[1]=(_Float16)nv0.y; h[2]=(_Float16)nv0.z; h[3]=(_Float16)nv0.w;
            h[4]=(_Float16)nv1.x; h[5]=(_Float16)nv1.y; h[6]=(_Float16)nv1.z; h[7]=(_Float16)nv1.w;
            *(half8*)((char*)Xt[(kc+1) & 1] + sdst) = h;
        }
        __syncthreads();
    }

    _Float16* tile16 = &Xt[0][0];
    #pragma unroll
    for (int qt = 0; qt < 2; ++qt){
        const int ql = qt*16 + l4*4;
        #pragma unroll
        for (int nt = 0; nt < 2; ++nt){
            const int n = w*32 + nt*16 + l15;
            const bool isQ = (n < 64);
            const float bias = isQ ? bq[n] : bk[n - 64];
            const float scale = isQ ? LOG2E : 1.0f;
            #pragma unroll
            for (int r = 0; r < 4; ++r)
                tile16[(ql + r)*128 + n] = (_Float16)((acc[qt][nt][r] + bias) * scale);
        }
    }
    __syncthreads();
    #pragma unroll
    for (int i = 0; i < 2; ++i){
        const int g = tid + 256*i;
        const int isK = g >> 8, qtl = (g >> 7) & 1, ks = (g >> 6) & 1, ln = g & 63;
        const int l4g = ln >> 4, l15g = ln & 15;
        const half8 h = *(const half8*)&tile16[(qtl*16 + l15g)*128 + isK*64 + ks*32 + l4g*8];
        const size_t tg = (size_t)b*128 + sb32*2 + qtl;
        _Float16* dst = (isK ? Kh2 : Qh2) + ((tg*2 + ks)*64 + ln)*8;
        *(half8*)dst = h;
    }
}

// ---- Kernel 2: per-(b,s) column denominators (base-2, fixed M0=64) ----
#define SBODY(QC0,QC1,QC2,QC3, QN0,QN1,QN2,QN3) do { \
    QN0 = *(const half8*)(Qp); \
    QN1 = *(const half8*)(Qp + 1024); \
    QN2 = *(const half8*)(Qp + 2048); \
    QN3 = *(const half8*)(Qp + 3072); \
    Qp += 8192; \
    f32x4 c0 = cinit, c1 = cinit; \
    c0 = MFMA16(ka0, QC0, c0); c0 = MFMA16(ka1, QC1, c0); \
    c1 = MFMA16(ka0, QC2, c1); c1 = MFMA16(ka1, QC3, c1); \
    _Pragma("unroll") \
    for (int r = 0; r < 4; ++r) \
        z[r] += exp2f(c0[r]) + exp2f(c1[r]); \
} while(0)

__global__ __launch_bounds__(512, 2) void stats_kernel(
    const _Float16* __restrict__ Qh2, const _Float16* __restrict__ Kh2,
    float* __restrict__ CS)
{
    __shared__ float zred[2][64];
    const int bid = blockIdx.x;
    const int b = bid & 7, stb = bid >> 3;
    const int tid = threadIdx.x, lane = tid & 63, w = tid >> 6;
    const int l15 = lane & 15, l4 = lane >> 4;
    const int sw = w & 3, qh = w >> 2, qh2 = qh*2;

    const half8 ka0 = *(const half8*)(Kh2 + ((size_t)((b*128 + stb*4 + sw)*2 + 0)*64 + lane)*8);
    const half8 ka1 = *(const half8*)(Kh2 + ((size_t)((b*128 + stb*4 + sw)*2 + 1)*64 + lane)*8);

    const char* Qp = (const char*)Qh2 + (size_t)(b*128 + qh2)*2048 + lane*16;

    const f32x4 cinit = {-64.f, -64.f, -64.f, -64.f};
    float z[4] = {0.f, 0.f, 0.f, 0.f};

    half8 qbA0, qbA1, qbA2, qbA3, qbB0, qbB1, qbB2, qbB3;
    qbA0 = *(const half8*)(Qp);
    qbA1 = *(const half8*)(Qp + 1024);
    qbA2 = *(const half8*)(Qp + 2048);
    qbA3 = *(const half8*)(Qp + 3072);
    Qp += 8192;

    for (int qc = 0; qc < 32; qc += 2){
        SBODY(qbA0,qbA1,qbA2,qbA3, qbB0,qbB1,qbB2,qbB3);
        SBODY(qbB0,qbB1,qbB2,qbB3, qbA0,qbA1,qbA2,qbA3);
    }
    #pragma unroll
    for (int d = 1; d < 16; d <<= 1)
        #pragma unroll
        for (int r = 0; r < 4; ++r)
            z[r] += __shfl_xor(z[r], d);
    if (l15 == 0){
        const int sl = sw*16 + l4*4;
        #pragma unroll
        for (int r = 0; r < 4; ++r) zred[qh][sl+r] = z[r];
    }
    __syncthreads();
    if (tid < 64)
        CS[b*Sn + stb*64 + tid] = -(64.0f + __log2f(zred[0][tid] + zred[1][tid]));
}

// ---- Kernel 3: attn, 128q x 128d blocks, 4 waves, 2 blocks/CU ----
// wave w: QK for s-subtile st=w (all 128 q), PV for d-slice [w*32, w*32+32)
#define WRP(CUR, QT, C) do { \
    half4v p; \
    p[0] = (_Float16)exp2f(C[0]); \
    p[1] = (_Float16)exp2f(C[1]); \
    p[2] = (_Float16)exp2f(C[2]); \
    p[3] = (_Float16)exp2f(C[3]); \
    *(half4v*)(PtB + (CUR)*16384 + (QT)*2048 + pw_base) = p; \
} while(0)

#define ABODY(CUR, KA, KAN, VB, VBN, CSA, CSN) do { \
    { \
        f32x4 c0 = {CSA.x, CSA.y, CSA.z, CSA.w}; \
        f32x4 c1 = c0, c2 = c0, c3 = c0; \
        c0 = MFMA16(KA[0], qb[0][0], c0); c0 = MFMA16(KA[1], qb[0][1], c0); \
        c1 = MFMA16(KA[0], qb[1][0], c1); c1 = MFMA16(KA[1], qb[1][1], c1); \
        c2 = MFMA16(KA[0], qb[2][0], c2); c2 = MFMA16(KA[1], qb[2][1], c2); \
        c3 = MFMA16(KA[0], qb[3][0], c3); c3 = MFMA16(KA[1], qb[3][1], c3); \
        KAN[0] = *(const half8*)(Kp); \
        KAN[1] = *(const half8*)(Kp + 1024); \
        Kp += 8192; \
        CSN = *(const float4*)Cp; Cp += 64; \
        WRP(CUR, 0, c0); WRP(CUR, 1, c1); WRP(CUR, 2, c2); WRP(CUR, 3, c3); \
    } \
    { \
        f32x4 c4 = {CSA.x, CSA.y, CSA.z, CSA.w}; \
        f32x4 c5 = c4, c6 = c4, c7 = c4; \
        c4 = MFMA16(KA[0], qb[4][0], c4); c4 = MFMA16(KA[1], qb[4][1], c4); \
        c5 = MFMA16(KA[0], qb[5][0], c5); c5 = MFMA16(KA[1], qb[5][1], c5); \
        c6 = MFMA16(KA[0], qb[6][0], c6); c6 = MFMA16(KA[1], qb[6][1], c6); \
        c7 = MFMA16(KA[0], qb[7][0], c7); c7 = MFMA16(KA[1], qb[7][1], c7); \
        WRP(CUR, 4, c4); WRP(CUR, 5, c5); WRP(CUR, 6, c6); WRP(CUR, 7, c7); \
    } \
    asm volatile("s_waitcnt lgkmcnt(0)\n\ts_barrier" ::: "memory"); \
    VBN[0] = *(const half8*)(Vp); \
    VBN[1] = *(const half8*)(Vp + 1024); \
    VBN[2] = *(const half8*)(Vp + 32768); \
    VBN[3] = *(const half8*)(Vp + 32768 + 1024); \
    Vp += 65536; \
    __builtin_amdgcn_s_setprio(1); \
    _Pragma("unroll") \
    for (int ks = 0; ks < 2; ++ks){ \
        const char* PB = PtB + (CUR)*16384 + (ks ? paoff1 : paoff0); \
        const half8 vb0 = VB[ks*2], vb1 = VB[ks*2+1]; \
        _Pragma("unroll") \
        for (int qt = 0; qt < 8; ++qt){ \
            const half8 pa = *(const half8*)(PB + qt*2048); \
            acc[qt][0] = MFMA16(pa, vb0, acc[qt][0]); \
            acc[qt][1] = MFMA16(pa, vb1, acc[qt][1]); \
        } \
    } \
    __builtin_amdgcn_s_setprio(0); \
} while(0)

__global__ __launch_bounds__(256, 2) void attn_kernel(
    const _Float16* __restrict__ Qh2, const _Float16* __restrict__ Kh2,
    const _Float16* __restrict__ Vt2, const float* __restrict__ CS,
    float* __restrict__ out)
{
    __shared__ _Float16 Pt[2][128*64];   // 32 KB -> 2 blocks/CU
    const int bid = blockIdx.x;
    const int b  = bid & 7;              // b-major -> one batch per XCD
    const int qi = (bid >> 3) & 15;      // 128-q tile
    const int dh = bid >> 7;             // 0..3 d-quarter (128 each)
    const int tid = threadIdx.x, lane = tid & 63, w = tid >> 6;  // w 0..3
    const int l15 = lane & 15, l4 = lane >> 4;
    char* PtB = (char*)Pt;

    // Q fragments: all 128 q (8 qt x 2 ks) -- held whole kernel
    const size_t qgb = (size_t)b*128 + qi*8;
    half8 qb[8][2];
    #pragma unroll
    for (int qt = 0; qt < 8; ++qt)
        #pragma unroll
        for (int ks = 0; ks < 2; ++ks)
            qb[qt][ks] = *(const half8*)(Qh2 + (((qgb + qt)*2 + ks)*64 + lane)*8);

    // P-tile base offsets (row q = qt*16 + l15 -> q&7 == l15&7, qt-independent)
    const int sb2 = (w*16 + l4*4) * 2;
    const int pw_base = l15*128 + (sb2 ^ ((l15 & 7) << 4));
    const int paoff0  = l15*128 + ((l4 ^ (l15 & 7)) << 4);
    const int paoff1  = paoff0 ^ 64;

    // streams (bumped pointers)
    const char* Kp = (const char*)Kh2 + (size_t)(b*128 + w)*2048 + lane*16;
    const float* Cp = CS + b*Sn + w*16 + l4*4;
    const char* Vp = (const char*)Vt2 + (size_t)(b*2048 + dh*8 + w*2)*1024 + lane*16;

    // prologue: K(0), CS(0), V(0)
    half8 kaA[2], kaB[2], vbA[4], vbB[4];
    float4 csA, csB;
    kaA[0] = *(const half8*)(Kp);
    kaA[1] = *(const half8*)(Kp + 1024);
    Kp += 8192;
    csA = *(const float4*)Cp; Cp += 64;
    vbA[0] = *(const half8*)(Vp);
    vbA[1] = *(const half8*)(Vp + 1024);
    vbA[2] = *(const half8*)(Vp + 32768);
    vbA[3] = *(const half8*)(Vp + 32768 + 1024);
    Vp += 65536;

    f32x4 acc[8][2];
    #pragma unroll
    for (int i = 0; i < 8; ++i)
        #pragma unroll
        for (int j = 0; j < 2; ++j){ f32x4 zz4 = {0.f,0.f,0.f,0.f}; acc[i][j] = zz4; }

    for (int sc = 0; sc < 32; sc += 2){
        ABODY(0, kaA, kaB, vbA, vbB, csA, csB);
        ABODY(1, kaB, kaA, vbB, vbA, csB, csA);
    }
    // (final iteration prefetches one tile past the end; lands in allocated ws)

    float* ob = out + (size_t)(b*Sn + qi*128)*Dn + dh*128 + w*32;
    #pragma unroll
    for (int qt = 0; qt < 8; ++qt){
        const int q = qt*16 + l4*4;
        #pragma unroll
        for (int dt = 0; dt < 2; ++dt){
            #pragma unroll
            for (int r = 0; r < 4; ++r)
                ob[(size_t)(q + r)*Dn + dt*16 + l15] = acc[qt][dt][r];
        }
    }
}

extern "C" void kernel_launch(void* const* d_in, const int* in_sizes, int n_in,
                              void* d_out, int out_size, void* d_ws, size_t ws_size,
                              hipStream_t stream)
{
    const float* X  = (const float*)d_in[0];
    const float* Wk = (const float*)d_in[1];
    const float* bk = (const float*)d_in[2];
    const float* Wq = (const float*)d_in[3];
    const float* bq = (const float*)d_in[4];
    float* out = (float*)d_out;

    char* ws = (char*)d_ws;
    _Float16* Qh2  = (_Float16*)ws;                                  // 2 MB
    _Float16* Kh2  = (_Float16*)(ws + ((size_t)2 << 20));            // 2 MB
    _Float16* Vt2  = (_Float16*)(ws + ((size_t)4 << 20));            // 16 MB (+1 MB overrun pad)
    float*    CS   = (float*)(ws + ((size_t)21 << 20));              // 64 KB (+64 KB guard)
    _Float16* Wt16 = (_Float16*)(ws + ((size_t)21 << 20) + (2 << 16)); // 128 KB

    wtrans_kernel<<<dim3(128), dim3(256), 0, stream>>>(Wk, Wq, Wt16);
    prep_kernel<<<dim3(Bn*(Sn/32)), dim3(256), 0, stream>>>(X, Wt16, bk, bq, Qh2, Kh2, Vt2);
    stats_kernel<<<dim3(Bn*(Sn/64)), dim3(512), 0, stream>>>(Qh2, Kh2, CS);
    attn_kernel<<<dim3(Bn*(Sn/128)*4), dim3(256), 0, stream>>>(Qh2, Kh2, Vt2, CS, out);
}

// Round 13
// 73.730 us; speedup vs baseline: 3.1444x; 1.3425x over previous
//
#include <hip/hip_runtime.h>
#include <hip/hip_bf16.h>

#define Bn 8
#define Sn 2048
#define Dn 512
#define Kn 64

typedef _Float16 half8 __attribute__((ext_vector_type(8)));
typedef _Float16 half4v __attribute__((ext_vector_type(4)));
typedef __fp16 fp16x2 __attribute__((ext_vector_type(2)));
typedef float f32x4 __attribute__((ext_vector_type(4)));

#define MFMA16(a,b,c) __builtin_amdgcn_mfma_f32_16x16x32_f16(a,b,c,0,0,0)
#define LOG2E 1.4426950408889634f
#define EXP2(x) __builtin_amdgcn_exp2f(x)

// LDS tiles [rows][64] f16 (128B rows), XOR-swizzled on 16B granules.
__device__ __forceinline__ half8 ldfrag(const _Float16* base, int row, int k8){
    const int scol = k8 ^ (row & 7);
    return *(const half8*)((const char*)base + row*128 + scol*16);
}

// Fragment layouts in global memory (16B granules, lane = l4*16+l15):
//  Qh2/Kh2: granule (t*2+ks)*64+lane = M[t*16+l15][ks*32+l4*8 .. +8]   (t = global 16-row tile)
//  Vt2:     granule (((b*32+sc)*2+ks)*32+dt)*64+lane = V[dt*16+l15][sc*64+(ks*4+l4)*8 .. +8]
// Q pre-scaled by log2(e). Stats: z[s] = sum_q 2^(l2-64); CS[s] = -(64+log2 z).
// attn: P[q,s] = 2^(l2[q,s] + CS[s]) via MFMA C-init; exp = raw v_exp_f32.

// ---- Kernel 0: W transpose+cast ----
__global__ __launch_bounds__(256) void wtrans_kernel(
    const float* __restrict__ Wk, const float* __restrict__ Wq,
    _Float16* __restrict__ Wt16)
{
    const int n = blockIdx.x;
    const int t = threadIdx.x;
    const float* src = (n < 64) ? Wq : Wk;
    const int nn = n & 63;
    #pragma unroll
    for (int i = 0; i < 2; ++i){
        const int k = t + 256*i;
        Wt16[(size_t)n*Dn + k] = (_Float16)src[(size_t)k*Kn + nn];
    }
}

// ---- Kernel 1: fused Q/K projection + V transpose (32 rows per block) ----
__global__ __launch_bounds__(256, 2) void prep_kernel(
    const float* __restrict__ X, const _Float16* __restrict__ Wt16,
    const float* __restrict__ bk, const float* __restrict__ bq,
    _Float16* __restrict__ Qh2, _Float16* __restrict__ Kh2,
    _Float16* __restrict__ Vt2)
{
    __shared__ _Float16 Xt[2][32*64];
    const int bid = blockIdx.x;
    const int b = bid & 7, sb32 = bid >> 3;
    const int tid = threadIdx.x, lane = tid & 63, w = tid >> 6;
    const int l15 = lane & 15, l4 = lane >> 4;

    const int srow = tid >> 3, sg = tid & 7;
    const float* Xs = X + ((size_t)(b*Sn + sb32*32) + srow)*Dn + sg*8;
    const int sdst = srow*128 + (((sg ^ (srow & 7) ^ (srow >> 3)) & 7) * 16);

    const int n0 = w*32 + l15;
    const _Float16* Wp0 = Wt16 + (size_t)n0*Dn + l4*8;
    const _Float16* Wp1 = Wp0 + (size_t)16*Dn;

    f32x4 acc[2][2];
    #pragma unroll
    for (int i = 0; i < 2; ++i)
        #pragma unroll
        for (int j = 0; j < 2; ++j){ f32x4 z = {0.f,0.f,0.f,0.f}; acc[i][j] = z; }

    {
        const float4 v0 = *(const float4*)(Xs);
        const float4 v1 = *(const float4*)(Xs + 4);
        half8 h;
        h[0]=(_Float16)v0.x; h[1]=(_Float16)v0.y; h[2]=(_Float16)v0.z; h[3]=(_Float16)v0.w;
        h[4]=(_Float16)v1.x; h[5]=(_Float16)v1.y; h[6]=(_Float16)v1.z; h[7]=(_Float16)v1.w;
        *(half8*)((char*)Xt[0] + sdst) = h;
    }
    __syncthreads();

    const int dcol = w*16 + l15;
    #pragma unroll
    for (int kc = 0; kc < 8; ++kc){
        const _Float16* XtC = Xt[kc & 1];
        float4 nv0, nv1;
        if (kc < 7){
            nv0 = *(const float4*)(Xs + (kc+1)*64);
            nv1 = *(const float4*)(Xs + (kc+1)*64 + 4);
        }
        const half8 wf00 = *(const half8*)(Wp0 + kc*64);
        const half8 wf01 = *(const half8*)(Wp0 + kc*64 + 32);
        const half8 wf10 = *(const half8*)(Wp1 + kc*64);
        const half8 wf11 = *(const half8*)(Wp1 + kc*64 + 32);
        #pragma unroll
        for (int ks = 0; ks < 2; ++ks){
            #pragma unroll
            for (int qt = 0; qt < 2; ++qt){
                const int rw = qt*16 + l15;
                const int g = ((ks*4 + l4) ^ (rw & 7) ^ (rw >> 3)) & 7;
                const half8 a = *(const half8*)((const char*)XtC + rw*128 + g*16);
                acc[qt][0] = MFMA16(a, ks ? wf01 : wf00, acc[qt][0]);
                acc[qt][1] = MFMA16(a, ks ? wf11 : wf10, acc[qt][1]);
            }
        }
        {
            half8 hv;
            #pragma unroll
            for (int e = 0; e < 8; ++e){
                const int rw = l4*8 + e;
                const int g = ((dcol >> 3) ^ e ^ l4) & 7;
                hv[e] = XtC[rw*64 + g*8 + (dcol & 7)];
            }
            const size_t G = (((size_t)(b*32 + (sb32 >> 1))*2 + (sb32 & 1))*32 + kc*4 + w)*64 + lane;
            *(half8*)(Vt2 + G*8) = hv;
        }
        if (kc < 7){
            half8 h;
            h[0]=(_Float16)nv0.x; h[1]=(_Float16)nv0.y; h[2]=(_Float16)nv0.z; h[3]=(_Float16)nv0.w;
            h[4]=(_Float16)nv1.x; h[5]=(_Float16)nv1.y; h[6]=(_Float16)nv1.z; h[7]=(_Float16)nv1.w;
            *(half8*)((char*)Xt[(kc+1) & 1] + sdst) = h;
        }
        __syncthreads();
    }

    _Float16* tile16 = &Xt[0][0];
    #pragma unroll
    for (int qt = 0; qt < 2; ++qt){
        const int ql = qt*16 + l4*4;
        #pragma unroll
        for (int nt = 0; nt < 2; ++nt){
            const int n = w*32 + nt*16 + l15;
            const bool isQ = (n < 64);
            const float bias = isQ ? bq[n] : bk[n - 64];
            const float scale = isQ ? LOG2E : 1.0f;
            #pragma unroll
            for (int r = 0; r < 4; ++r)
                tile16[(ql + r)*128 + n] = (_Float16)((acc[qt][nt][r] + bias) * scale);
        }
    }
    __syncthreads();
    #pragma unroll
    for (int i = 0; i < 2; ++i){
        const int g = tid + 256*i;
        const int isK = g >> 8, qtl = (g >> 7) & 1, ks = (g >> 6) & 1, ln = g & 63;
        const int l4g = ln >> 4, l15g = ln & 15;
        const half8 h = *(const half8*)&tile16[(qtl*16 + l15g)*128 + isK*64 + ks*32 + l4g*8];
        const size_t tg = (size_t)b*128 + sb32*2 + qtl;
        _Float16* dst = (isK ? Kh2 : Qh2) + ((tg*2 + ks)*64 + ln)*8;
        *(half8*)dst = h;
    }
}

// ---- Kernel 2: per-(b,s) column denominators (base-2, fixed M0=64) ----
#define SBODY(QC0,QC1,QC2,QC3, QN0,QN1,QN2,QN3) do { \
    QN0 = *(const half8*)(Qp); \
    QN1 = *(const half8*)(Qp + 1024); \
    QN2 = *(const half8*)(Qp + 2048); \
    QN3 = *(const half8*)(Qp + 3072); \
    Qp += 8192; \
    f32x4 c0 = cinit, c1 = cinit; \
    c0 = MFMA16(ka0, QC0, c0); c0 = MFMA16(ka1, QC1, c0); \
    c1 = MFMA16(ka0, QC2, c1); c1 = MFMA16(ka1, QC3, c1); \
    _Pragma("unroll") \
    for (int r = 0; r < 4; ++r) \
        z[r] += EXP2(c0[r]) + EXP2(c1[r]); \
} while(0)

__global__ __launch_bounds__(512, 2) void stats_kernel(
    const _Float16* __restrict__ Qh2, const _Float16* __restrict__ Kh2,
    float* __restrict__ CS)
{
    __shared__ float zred[2][64];
    const int bid = blockIdx.x;
    const int b = bid & 7, stb = bid >> 3;
    const int tid = threadIdx.x, lane = tid & 63, w = tid >> 6;
    const int l15 = lane & 15, l4 = lane >> 4;
    const int sw = w & 3, qh = w >> 2, qh2 = qh*2;

    const half8 ka0 = *(const half8*)(Kh2 + ((size_t)((b*128 + stb*4 + sw)*2 + 0)*64 + lane)*8);
    const half8 ka1 = *(const half8*)(Kh2 + ((size_t)((b*128 + stb*4 + sw)*2 + 1)*64 + lane)*8);

    const char* Qp = (const char*)Qh2 + (size_t)(b*128 + qh2)*2048 + lane*16;

    const f32x4 cinit = {-64.f, -64.f, -64.f, -64.f};
    float z[4] = {0.f, 0.f, 0.f, 0.f};

    half8 qbA0, qbA1, qbA2, qbA3, qbB0, qbB1, qbB2, qbB3;
    qbA0 = *(const half8*)(Qp);
    qbA1 = *(const half8*)(Qp + 1024);
    qbA2 = *(const half8*)(Qp + 2048);
    qbA3 = *(const half8*)(Qp + 3072);
    Qp += 8192;

    for (int qc = 0; qc < 32; qc += 2){
        SBODY(qbA0,qbA1,qbA2,qbA3, qbB0,qbB1,qbB2,qbB3);
        SBODY(qbB0,qbB1,qbB2,qbB3, qbA0,qbA1,qbA2,qbA3);
    }
    #pragma unroll
    for (int d = 1; d < 16; d <<= 1)
        #pragma unroll
        for (int r = 0; r < 4; ++r)
            z[r] += __shfl_xor(z[r], d);
    if (l15 == 0){
        const int sl = sw*16 + l4*4;
        #pragma unroll
        for (int r = 0; r < 4; ++r) zred[qh][sl+r] = z[r];
    }
    __syncthreads();
    if (tid < 64)
        CS[b*Sn + stb*64 + tid] = -(64.0f + __log2f(zred[0][tid] + zred[1][tid]));
}

// ---- Kernel 3: fused logits -> P -> P@V; 4-wave 64q x 256d blocks ----
#define WRP(PT, QT, C) do { \
    const float e0 = EXP2(C[0]); \
    const float e1 = EXP2(C[1]); \
    const float e2 = EXP2(C[2]); \
    const float e3 = EXP2(C[3]); \
    const fp16x2 plo = __builtin_amdgcn_cvt_pkrtz(e0, e1); \
    const fp16x2 phi = __builtin_amdgcn_cvt_pkrtz(e2, e3); \
    uint2 pu; \
    pu.x = __builtin_bit_cast(unsigned int, plo); \
    pu.y = __builtin_bit_cast(unsigned int, phi); \
    *(uint2*)((char*)(PT) + (QT)*2048 + pw_base) = pu; \
} while(0)

#define ABODY(KA, KAN, VB, VBN, CSA, CSN, PT) do { \
    f32x4 c0 = {CSA.x, CSA.y, CSA.z, CSA.w}; \
    f32x4 c1 = c0, c2 = c0, c3 = c0; \
    c0 = MFMA16(KA[0], qb[0][0], c0); c0 = MFMA16(KA[1], qb[0][1], c0); \
    c1 = MFMA16(KA[0], qb[1][0], c1); c1 = MFMA16(KA[1], qb[1][1], c1); \
    c2 = MFMA16(KA[0], qb[2][0], c2); c2 = MFMA16(KA[1], qb[2][1], c2); \
    c3 = MFMA16(KA[0], qb[3][0], c3); c3 = MFMA16(KA[1], qb[3][1], c3); \
    KAN[0] = *(const half8*)(Kp); \
    KAN[1] = *(const half8*)(Kp + 1024); \
    Kp += 8192; \
    CSN = *(const float4*)Cp; Cp += 64; \
    WRP(PT, 0, c0); WRP(PT, 1, c1); \
    WRP(PT, 2, c2); WRP(PT, 3, c3); \
    asm volatile("s_waitcnt lgkmcnt(0)\n\ts_barrier" ::: "memory"); \
    _Pragma("unroll") \
    for (int d_ = 0; d_ < 4; ++d_){ \
        VBN[d_]   = *(const half8*)(Vp0 + d_*1024); \
        VBN[4+d_] = *(const half8*)(Vp1 + d_*1024); \
    } \
    Vp0 += 65536; Vp1 += 65536; \
    __builtin_amdgcn_s_setprio(1); \
    { const char* PB = (const char*)(PT); \
      _Pragma("unroll") \
      for (int ks = 0; ks < 2; ++ks){ \
        const int po = ks ? paoff1 : paoff0; \
        const half8 pa0 = *(const half8*)(PB + 0*2048 + po); \
        const half8 pa1 = *(const half8*)(PB + 1*2048 + po); \
        const half8 pa2 = *(const half8*)(PB + 2*2048 + po); \
        const half8 pa3 = *(const half8*)(PB + 3*2048 + po); \
        _Pragma("unroll") \
        for (int d_ = 0; d_ < 4; ++d_){ \
            acc[0][d_] = MFMA16(pa0, VB[ks*4+d_], acc[0][d_]); \
            acc[1][d_] = MFMA16(pa1, VB[ks*4+d_], acc[1][d_]); \
            acc[2][d_] = MFMA16(pa2, VB[ks*4+d_], acc[2][d_]); \
            acc[3][d_] = MFMA16(pa3, VB[ks*4+d_], acc[3][d_]); \
        } \
      } } \
    __builtin_amdgcn_s_setprio(0); \
} while(0)

__global__ __launch_bounds__(256, 2) void attn_kernel(
    const _Float16* __restrict__ Qh2, const _Float16* __restrict__ Kh2,
    const _Float16* __restrict__ Vt2, const float* __restrict__ CS,
    float* __restrict__ out)
{
    __shared__ _Float16 Pt[2][64*64];   // 16 KB
    const int bid = blockIdx.x;
    const int b  = bid & 7;             // b-major -> one batch per XCD
    const int qi = (bid >> 3) & 31;
    const int dh = bid >> 8;            // 0..1 d-half
    const int q0 = qi * 64;
    const int tid = threadIdx.x, lane = tid & 63, w = tid >> 6;   // w 0..3
    const int l15 = lane & 15, l4 = lane >> 4;
    const int soff = w*16 + l4*4;       // s offset within tile (wave owns s-tile w)
    const int sb2  = soff * 2;
    // P-tile offsets (q_ = QT*16+l15 -> q_&7 == l15&7, QT-independent)
    const int pw_base = l15*128 + (sb2 ^ ((l15 & 7) << 4));
    const int paoff0  = l15*128 + ((l4 ^ (l15 & 7)) << 4);
    const int paoff1  = paoff0 ^ 64;

    // Q fragments (held whole kernel)
    const size_t qgb = (size_t)b*128 + qi*4;
    half8 qb[4][2];
    #pragma unroll
    for (int qt = 0; qt < 4; ++qt)
        #pragma unroll
        for (int ks = 0; ks < 2; ++ks)
            qb[qt][ks] = *(const half8*)(Qh2 + (((qgb + qt)*2 + ks)*64 + lane)*8);

    // bumped pointers (point at next tile to fetch)
    const char* Kp  = (const char*)Kh2 + (size_t)(b*128 + w)*2048 + lane*16;
    const char* Vp0 = (const char*)Vt2 + (size_t)(b*2048 + dh*16 + w*4)*1024 + lane*16;
    const char* Vp1 = Vp0 + 32768;
    const float* Cp = CS + b*Sn + soff;

    // prologue: prefetch sc=0
    half8 kaA[2], kaB[2], vbA[8], vbB[8];
    float4 csA, csB;
    kaA[0] = *(const half8*)(Kp);
    kaA[1] = *(const half8*)(Kp + 1024);
    Kp += 8192;
    #pragma unroll
    for (int d_ = 0; d_ < 4; ++d_){
        vbA[d_]   = *(const half8*)(Vp0 + d_*1024);
        vbA[4+d_] = *(const half8*)(Vp1 + d_*1024);
    }
    Vp0 += 65536; Vp1 += 65536;
    csA = *(const float4*)Cp; Cp += 64;

    f32x4 acc[4][4];
    #pragma unroll
    for (int i = 0; i < 4; ++i)
        #pragma unroll
        for (int j = 0; j < 4; ++j){ f32x4 zz4 = {0.f,0.f,0.f,0.f}; acc[i][j] = zz4; }

    for (int it = 0; it < 16; ++it){
        ABODY(kaA, kaB, vbA, vbB, csA, csB, Pt[0]);
        ABODY(kaB, kaA, vbB, vbA, csB, csA, Pt[1]);
    }

    float* ob = out + (size_t)(b*Sn + q0)*Dn + dh*256 + w*64;
    #pragma unroll
    for (int qt = 0; qt < 4; ++qt){
        const int q = qt*16 + l4*4;
        #pragma unroll
        for (int d_ = 0; d_ < 4; ++d_){
            #pragma unroll
            for (int r = 0; r < 4; ++r)
                ob[(size_t)(q + r)*Dn + d_*16 + l15] = acc[qt][d_][r];
        }
    }
}

extern "C" void kernel_launch(void* const* d_in, const int* in_sizes, int n_in,
                              void* d_out, int out_size, void* d_ws, size_t ws_size,
                              hipStream_t stream)
{
    const float* X  = (const float*)d_in[0];
    const float* Wk = (const float*)d_in[1];
    const float* bk = (const float*)d_in[2];
    const float* Wq = (const float*)d_in[3];
    const float* bq = (const float*)d_in[4];
    float* out = (float*)d_out;

    char* ws = (char*)d_ws;
    _Float16* Qh2  = (_Float16*)ws;                                  // 2 MB
    _Float16* Kh2  = (_Float16*)(ws + ((size_t)2 << 20));            // 2 MB
    _Float16* Vt2  = (_Float16*)(ws + ((size_t)4 << 20));            // 16 MB
    float*    CS   = (float*)(ws + ((size_t)20 << 20));              // 64 KB (+64 KB guard)
    _Float16* Wt16 = (_Float16*)(ws + ((size_t)20 << 20) + (2 << 16)); // 128 KB

    wtrans_kernel<<<dim3(128), dim3(256), 0, stream>>>(Wk, Wq, Wt16);
    prep_kernel<<<dim3(Bn*(Sn/32)), dim3(256), 0, stream>>>(X, Wt16, bk, bq, Qh2, Kh2, Vt2);
    stats_kernel<<<dim3(Bn*(Sn/64)), dim3(512), 0, stream>>>(Qh2, Kh2, CS);
    attn_kernel<<<dim3(Bn*(Sn/64)*2), dim3(256), 0, stream>>>(Qh2, Kh2, Vt2, CS, out);
}